// Round 1
// baseline (2255.037 us; speedup 1.0000x reference)
//
#include <hip/hip_runtime.h>
#include <math.h>

// NerfactoModel fused forward. N=2e6 samples, 16-level hash encode (mod 4096),
// dens MLP 32->64->64->16, dir MLP 3->16->16, col MLP 63->64->64->3.
// One thread per sample; fully unrolled so activations live in VGPRs and
// weight loads become scalar (wave-uniform) s_load through the constant path.

struct Res16 { int r[16]; };

#define PRIME_Y 2481   // 2654435761 % 4096
#define PRIME_Z 1941   // 805459861 % 4096

__global__ __launch_bounds__(256, 2)
void nerf_fwd(const float* __restrict__ ray_samples,
              const float* __restrict__ directions,
              const int*   __restrict__ cam_idx,
              const float* __restrict__ aabb,
              const float* __restrict__ hash_tables,
              const float* __restrict__ dir_w1, const float* __restrict__ dir_b1,
              const float* __restrict__ dir_w2, const float* __restrict__ dir_b2,
              const float* __restrict__ dens_w1, const float* __restrict__ dens_b1,
              const float* __restrict__ dens_w2, const float* __restrict__ dens_b2,
              const float* __restrict__ dens_w3, const float* __restrict__ dens_b3,
              const float* __restrict__ col_w1, const float* __restrict__ col_b1,
              const float* __restrict__ col_w2, const float* __restrict__ col_b2,
              const float* __restrict__ col_w3, const float* __restrict__ col_b3,
              const float* __restrict__ app_emb,
              float* __restrict__ out,
              int n_samples, Res16 res)
{
    const int n = blockIdx.x * 256 + threadIdx.x;
    if (n >= n_samples) return;

    // ---- positions = clip((rs - aabb0) / (aabb1 - aabb0), 0, 1) ----
    const float a0x = aabb[0], a0y = aabb[1], a0z = aabb[2];
    const float a1x = aabb[3], a1y = aabb[4], a1z = aabb[5];
    const float rx = ray_samples[3*n+0];
    const float ry = ray_samples[3*n+1];
    const float rz = ray_samples[3*n+2];
    float px = (rx - a0x) / (a1x - a0x);
    float py = (ry - a0y) / (a1y - a0y);
    float pz = (rz - a0z) / (a1z - a0z);
    px = fminf(fmaxf(px, 0.f), 1.f);
    py = fminf(fmaxf(py, 0.f), 1.f);
    pz = fminf(fmaxf(pz, 0.f), 1.f);

    // ---- hash encoding: 16 levels x 2 feats ----
    float enc[32];
    #pragma unroll
    for (int l = 0; l < 16; ++l) {
        const int r = res.r[l];
        const float rf = (float)(r - 1);
        int cx = (int)floorf(px * rf);
        int cy = (int)floorf(py * rf);
        int cz = (int)floorf(pz * rf);
        cx = min(max(cx, 0), r - 1);
        cy = min(max(cy, 0), r - 1);
        cz = min(max(cz, 0), r - 1);
        const int h = (cx + cy * PRIME_Y + cz * PRIME_Z) & 4095;
        const float2 f = *(const float2*)(hash_tables + (size_t)((l << 12) + h) * 2);
        enc[2*l+0] = f.x;
        enc[2*l+1] = f.y;
    }

    // ---- density MLP layer 1: 32 -> 64, relu ----
    float h1[64];
    #pragma unroll
    for (int j = 0; j < 64; ++j) h1[j] = dens_b1[j];
    #pragma unroll
    for (int i = 0; i < 32; ++i) {
        const float e = enc[i];
        #pragma unroll
        for (int j = 0; j < 64; ++j) h1[j] = fmaf(e, dens_w1[i*64+j], h1[j]);
    }
    #pragma unroll
    for (int j = 0; j < 64; ++j) h1[j] = fmaxf(h1[j], 0.f);

    // ---- density MLP layer 2: 64 -> 64, relu ----
    float h2[64];
    #pragma unroll
    for (int j = 0; j < 64; ++j) h2[j] = dens_b2[j];
    #pragma unroll
    for (int i = 0; i < 64; ++i) {
        const float e = h1[i];
        #pragma unroll
        for (int j = 0; j < 64; ++j) h2[j] = fmaf(e, dens_w2[i*64+j], h2[j]);
    }
    #pragma unroll
    for (int j = 0; j < 64; ++j) h2[j] = fmaxf(h2[j], 0.f);

    // ---- density MLP layer 3: 64 -> 16 (no relu) ----
    float df[16];
    #pragma unroll
    for (int j = 0; j < 16; ++j) df[j] = dens_b3[j];
    #pragma unroll
    for (int i = 0; i < 64; ++i) {
        const float e = h2[i];
        #pragma unroll
        for (int j = 0; j < 16; ++j) df[j] = fmaf(e, dens_w3[i*16+j], df[j]);
    }

    // density + geo written immediately (frees pressure)
    out[19*(size_t)n + 3] = fmaxf(df[0], 0.f);
    #pragma unroll
    for (int j = 0; j < 15; ++j) out[19*(size_t)n + 4 + j] = df[j+1];

    // ---- dir MLP: 3 -> 16 relu -> 16 (no relu) ----
    const float dx = directions[3*n+0];
    const float dy = directions[3*n+1];
    const float dz = directions[3*n+2];
    float e1[16];
    #pragma unroll
    for (int j = 0; j < 16; ++j) {
        float v = dir_b1[j];
        v = fmaf(dx, dir_w1[0*16+j], v);
        v = fmaf(dy, dir_w1[1*16+j], v);
        v = fmaf(dz, dir_w1[2*16+j], v);
        e1[j] = fmaxf(v, 0.f);
    }
    float ed[16];
    #pragma unroll
    for (int j = 0; j < 16; ++j) ed[j] = dir_b2[j];
    #pragma unroll
    for (int i = 0; i < 16; ++i) {
        const float e = e1[i];
        #pragma unroll
        for (int j = 0; j < 16; ++j) ed[j] = fmaf(e, dir_w2[i*16+j], ed[j]);
    }

    // ---- cin = [geo(15), edir(16), app_emb[cam](32)] ----
    float cin[63];
    #pragma unroll
    for (int j = 0; j < 15; ++j) cin[j] = df[j+1];
    #pragma unroll
    for (int j = 0; j < 16; ++j) cin[15+j] = ed[j];
    const int cam = cam_idx[n];
    const float4* ap = (const float4*)(app_emb + (size_t)cam * 32);
    #pragma unroll
    for (int q = 0; q < 8; ++q) {
        const float4 v = ap[q];
        cin[31+4*q+0] = v.x; cin[31+4*q+1] = v.y;
        cin[31+4*q+2] = v.z; cin[31+4*q+3] = v.w;
    }

    // ---- color MLP layer 1: 63 -> 64, relu ----
    float c1[64];
    #pragma unroll
    for (int j = 0; j < 64; ++j) c1[j] = col_b1[j];
    #pragma unroll
    for (int i = 0; i < 63; ++i) {
        const float e = cin[i];
        #pragma unroll
        for (int j = 0; j < 64; ++j) c1[j] = fmaf(e, col_w1[i*64+j], c1[j]);
    }
    #pragma unroll
    for (int j = 0; j < 64; ++j) c1[j] = fmaxf(c1[j], 0.f);

    // ---- color MLP layer 2: 64 -> 64, relu ----
    float c2[64];
    #pragma unroll
    for (int j = 0; j < 64; ++j) c2[j] = col_b2[j];
    #pragma unroll
    for (int i = 0; i < 64; ++i) {
        const float e = c1[i];
        #pragma unroll
        for (int j = 0; j < 64; ++j) c2[j] = fmaf(e, col_w2[i*64+j], c2[j]);
    }
    #pragma unroll
    for (int j = 0; j < 64; ++j) c2[j] = fmaxf(c2[j], 0.f);

    // ---- color MLP layer 3: 64 -> 3, sigmoid ----
    float rgb[3];
    #pragma unroll
    for (int k = 0; k < 3; ++k) rgb[k] = col_b3[k];
    #pragma unroll
    for (int i = 0; i < 64; ++i) {
        const float e = c2[i];
        #pragma unroll
        for (int k = 0; k < 3; ++k) rgb[k] = fmaf(e, col_w3[i*3+k], rgb[k]);
    }
    #pragma unroll
    for (int k = 0; k < 3; ++k)
        out[19*(size_t)n + k] = 1.f / (1.f + expf(-rgb[k]));
}

extern "C" void kernel_launch(void* const* d_in, const int* in_sizes, int n_in,
                              void* d_out, int out_size, void* d_ws, size_t ws_size,
                              hipStream_t stream)
{
    const float* ray  = (const float*)d_in[0];
    const float* dirs = (const float*)d_in[1];
    const int*   cam  = (const int*)  d_in[2];
    const float* aabb = (const float*)d_in[3];
    const float* ht   = (const float*)d_in[4];
    const float* dw1  = (const float*)d_in[5];
    const float* db1  = (const float*)d_in[6];
    const float* dw2  = (const float*)d_in[7];
    const float* db2  = (const float*)d_in[8];
    const float* nw1  = (const float*)d_in[9];
    const float* nb1  = (const float*)d_in[10];
    const float* nw2  = (const float*)d_in[11];
    const float* nb2  = (const float*)d_in[12];
    const float* nw3  = (const float*)d_in[13];
    const float* nb3  = (const float*)d_in[14];
    const float* cw1  = (const float*)d_in[15];
    const float* cb1  = (const float*)d_in[16];
    const float* cw2  = (const float*)d_in[17];
    const float* cb2  = (const float*)d_in[18];
    const float* cw3  = (const float*)d_in[19];
    const float* cb3  = (const float*)d_in[20];
    const float* app  = (const float*)d_in[21];
    float* out = (float*)d_out;

    const int n = in_sizes[0] / 3;

    // Reproduce Python's RES computation bit-exactly (same libm on this host):
    // GROWTH = exp((log(2048)-log(16))/15); RES[i] = int(16 * GROWTH**i)
    Res16 res;
    const double growth = exp((log(2048.0) - log(16.0)) / 15.0);
    for (int i = 0; i < 16; ++i)
        res.r[i] = (int)(16.0 * pow(growth, (double)i));

    const int grid = (n + 255) / 256;
    nerf_fwd<<<grid, 256, 0, stream>>>(
        ray, dirs, cam, aabb, ht,
        dw1, db1, dw2, db2,
        nw1, nb1, nw2, nb2, nw3, nb3,
        cw1, cb1, cw2, cb2, cw3, cb3,
        app, out, n, res);
}

// Round 2
// 439.966 us; speedup vs baseline: 5.1255x; 5.1255x over previous
//
#include <hip/hip_runtime.h>
#include <math.h>

// NerfactoModel fused forward, MFMA version.
// Per wave: 64 samples. Activations in per-wave LDS [64 x 72 bf16, stride 144B]
// (B-fragment layout: n = sample = lane&15, k = feat = (lane>>4)*8+e).
// Weights staged as bf16 transposed Wt[out][in] (A-layout: m = out = lane&15).
// The three 64x64 layers' A-frags are persisted in VGPRs, so their LDS staging
// area is reused for the act buffers (total static LDS = 47712 B).
// cin feature permutation (matched in col_w1 staging):
//   app -> slots 0..31, edir -> 32..47, pad(0) -> 48, geo -> 49..63.

typedef short short8 __attribute__((ext_vector_type(8)));
typedef float f32x4 __attribute__((ext_vector_type(4)));
typedef unsigned int uint;
typedef unsigned short ushort;

struct EncC { float rf[16]; };   // (RES[l]-1) as float

#define PY 2481   // 2654435761 % 4096
#define PZ 1941   // 805459861 % 4096

#define MFMA(A,B,C) __builtin_amdgcn_mfma_f32_16x16x32_bf16(A, B, C, 0, 0, 0)

// ---- LDS layout (bytes) ----
#define W1_OFF   0        // dens_w1^T  64 x 40 bf16 (5120)
#define W3_OFF   5120     // dens_w3^T  16 x 72 bf16 (2304)
#define C3_OFF   7424     // col_w3^T   16 x 72 bf16 (2304)
#define DB1_OFF  9728     // f32 biases
#define DB2_OFF  9984
#define DB3_OFF  10240
#define CB1_OFF  10304
#define CB2_OFF  10560
#define CB3_OFF  10816
// staging-only region (freed after A-frag preload), reused by ACT:
#define W2_OFF   10848    // dens_w2^T  64 x 72 (9216)
#define C1_OFF   20064    // col_w1^T (permuted K) 64 x 72 (9216)
#define C2_OFF   29280    // col_w2^T   64 x 72 (9216)
#define ACT_OFF  10848    // 4 waves x 64 rows x 144 B = 36864
#define LDS_BYTES 47712

__device__ __forceinline__ uint bf16rne(float x) {
    uint u = __builtin_bit_cast(uint, x);
    return (u + 0x7fffu + ((u >> 16) & 1u)) >> 16;
}
__device__ __forceinline__ uint packbf(float lo, float hi) {
    return bf16rne(lo) | (bf16rne(hi) << 16);
}

// writeback for a 64-out layer: bias + relu + bf16 pack, in place.
__device__ __forceinline__ void layer_wb(const f32x4* acc, const char* biasp,
                                         char* rowp, int q) {
#pragma unroll
    for (int mt = 0; mt < 4; ++mt) {
        f32x4 bb = *(const f32x4*)(biasp + mt*64 + q*16);
        f32x4 v = acc[mt] + bb;
        uint2 pw;
        pw.x = packbf(fmaxf(v[0], 0.f), fmaxf(v[1], 0.f));
        pw.y = packbf(fmaxf(v[2], 0.f), fmaxf(v[3], 0.f));
        *(uint2*)(rowp + (mt*16 + q*4)*2) = pw;
    }
}

// full 64->64 layer (K=64), A-frags persistent in registers.
__device__ __forceinline__ void layer64(char* wact, const short8* aw,
                                        const char* biasp, int l15, int q) {
    const int q16 = q * 16;
#pragma unroll
    for (int nt = 0; nt < 4; ++nt) {
        char* rowp = wact + (nt*16 + l15)*144;
        short8 b0 = *(const short8*)(rowp + q16);
        short8 b1 = *(const short8*)(rowp + 64 + q16);
        f32x4 acc[4];
#pragma unroll
        for (int mt = 0; mt < 4; ++mt) {
            f32x4 z = {0.f, 0.f, 0.f, 0.f};
            z = MFMA(aw[2*mt], b0, z);
            acc[mt] = MFMA(aw[2*mt + 1], b1, z);
        }
        layer_wb(acc, biasp, rowp, q);
    }
}

__global__ __launch_bounds__(256, 2)
void nerf_mfma(const float* __restrict__ ray, const float* __restrict__ dirs,
               const int* __restrict__ cam_idx, const float* __restrict__ aabb,
               const float* __restrict__ ht,
               const float* __restrict__ dir_w1, const float* __restrict__ dir_b1,
               const float* __restrict__ dir_w2, const float* __restrict__ dir_b2,
               const float* __restrict__ dens_w1, const float* __restrict__ dens_b1,
               const float* __restrict__ dens_w2, const float* __restrict__ dens_b2,
               const float* __restrict__ dens_w3, const float* __restrict__ dens_b3,
               const float* __restrict__ col_w1, const float* __restrict__ col_b1,
               const float* __restrict__ col_w2, const float* __restrict__ col_b2,
               const float* __restrict__ col_w3, const float* __restrict__ col_b3,
               const float* __restrict__ app_emb,
               float* __restrict__ out, int n, EncC enc)
{
    __shared__ __align__(16) char smem[LDS_BYTES];
    const int t = threadIdx.x;

    // ---- zero weight staging area (pad slots must read as 0) ----
    {
        uint* z = (uint*)smem;
        for (int i = t; i < 38496/4; i += 256) z[i] = 0;
    }
    __syncthreads();
    // ---- stage weights: bf16, transposed [out][in] ----
    {
        ushort* w1t = (ushort*)(smem + W1_OFF);
        for (int e = t; e < 2048; e += 256) w1t[(e&63)*40 + (e>>6)] = (ushort)bf16rne(dens_w1[e]);
        ushort* w2t = (ushort*)(smem + W2_OFF);
        for (int e = t; e < 4096; e += 256) w2t[(e&63)*72 + (e>>6)] = (ushort)bf16rne(dens_w2[e]);
        ushort* w3t = (ushort*)(smem + W3_OFF);
        for (int e = t; e < 1024; e += 256) w3t[(e&15)*72 + (e>>4)] = (ushort)bf16rne(dens_w3[e]);
        ushort* c1t = (ushort*)(smem + C1_OFF);
        for (int e = t; e < 4032; e += 256) {
            int in = e >> 6, o = e & 63;
            int pk = (in < 15) ? (in + 49) : ((in < 31) ? (in + 17) : (in - 31));
            c1t[o*72 + pk] = (ushort)bf16rne(col_w1[e]);
        }
        ushort* c2t = (ushort*)(smem + C2_OFF);
        for (int e = t; e < 4096; e += 256) c2t[(e&63)*72 + (e>>6)] = (ushort)bf16rne(col_w2[e]);
        ushort* c3t = (ushort*)(smem + C3_OFF);
        for (int e = t; e < 192; e += 256) c3t[(e%3)*72 + (e/3)] = (ushort)bf16rne(col_w3[e]);
        if (t < 64) {
            *(float*)(smem + DB1_OFF + t*4) = dens_b1[t];
            *(float*)(smem + DB2_OFF + t*4) = dens_b2[t];
            *(float*)(smem + CB1_OFF + t*4) = col_b1[t];
            *(float*)(smem + CB2_OFF + t*4) = col_b2[t];
        }
        if (t < 16) *(float*)(smem + DB3_OFF + t*4) = dens_b3[t];
        if (t < 4)  *(float*)(smem + CB3_OFF + t*4) = (t < 3) ? col_b3[t] : 0.f;
    }
    __syncthreads();

    const int w = t >> 6, lane = t & 63, l15 = lane & 15, q = lane >> 4;
    const int q16 = q * 16;
    char* wact = smem + ACT_OFF + w*9216;

    // ---- preload persistent A-frags for the three 64x64 layers (96 VGPRs) ----
    short8 aD2[8], aC1[8], aC2[8];
#pragma unroll
    for (int mt = 0; mt < 4; ++mt)
#pragma unroll
        for (int kk = 0; kk < 2; ++kk) {
            const int ro = (mt*16 + l15)*144 + kk*64 + q16;
            aD2[mt*2+kk] = *(const short8*)(smem + W2_OFF + ro);
            aC1[mt*2+kk] = *(const short8*)(smem + C1_OFF + ro);
            aC2[mt*2+kk] = *(const short8*)(smem + C2_OFF + ro);
        }
    __syncthreads();   // staging area now reusable as act buffers

    const float a0x = aabb[0], a0y = aabb[1], a0z = aabb[2];
    const float ivx = 1.f/(aabb[3]-a0x), ivy = 1.f/(aabb[4]-a0y), ivz = 1.f/(aabb[5]-a0z);

    const int ntiles = (n + 255) >> 8;
    for (int tile = blockIdx.x; tile < ntiles; tile += gridDim.x) {
        const int base = tile*256 + w*64;
        if (base >= n) continue;           // wave-uniform
        const int s  = base + lane;
        const int sc = min(s, n - 1);

        // ---- hash encoding -> act feats 0..31 ----
        float px = fminf(fmaxf((ray[3*sc  ] - a0x)*ivx, 0.f), 1.f);
        float py = fminf(fmaxf((ray[3*sc+1] - a0y)*ivy, 0.f), 1.f);
        float pz = fminf(fmaxf((ray[3*sc+2] - a0z)*ivz, 0.f), 1.f);
        uint encp[16];
#pragma unroll
        for (int l = 0; l < 16; ++l) {
            const float rf = enc.rf[l];
            const int cx = (int)(px*rf), cy = (int)(py*rf), cz = (int)(pz*rf);
            const int h = (cx + cy*PY + cz*PZ) & 4095;
            const float2 f = *(const float2*)(ht + (((l<<12) + h) << 1));
            encp[l] = packbf(f.x, f.y);
        }
        uint4* arow = (uint4*)(wact + lane*144);
        arow[0] = make_uint4(encp[0],  encp[1],  encp[2],  encp[3]);
        arow[1] = make_uint4(encp[4],  encp[5],  encp[6],  encp[7]);
        arow[2] = make_uint4(encp[8],  encp[9],  encp[10], encp[11]);
        arow[3] = make_uint4(encp[12], encp[13], encp[14], encp[15]);

        // ---- dens1: 32 -> 64, relu (K=32) ----
        {
            short8 a1[4];
#pragma unroll
            for (int mt = 0; mt < 4; ++mt)
                a1[mt] = *(const short8*)(smem + W1_OFF + (mt*16 + l15)*80 + q16);
#pragma unroll
            for (int nt = 0; nt < 4; ++nt) {
                char* rowp = wact + (nt*16 + l15)*144;
                short8 b = *(const short8*)(rowp + q16);
                f32x4 acc[4];
#pragma unroll
                for (int mt = 0; mt < 4; ++mt) {
                    f32x4 z = {0.f, 0.f, 0.f, 0.f};
                    acc[mt] = MFMA(a1[mt], b, z);
                }
                layer_wb(acc, smem + DB1_OFF, rowp, q);
            }
        }
        // ---- dens2: 64 -> 64, relu ----
        layer64(wact, aD2, smem + DB2_OFF, l15, q);
        // ---- dens3: 64 -> 16 ; density+geo out, geo -> cin slots 49..63 ----
        {
            short8 a0 = *(const short8*)(smem + W3_OFF + l15*144 + q16);
            short8 a1 = *(const short8*)(smem + W3_OFF + l15*144 + 64 + q16);
            f32x4 bb3 = *(const f32x4*)(smem + DB3_OFF + q16);
#pragma unroll
            for (int nt = 0; nt < 4; ++nt) {
                char* rowp = wact + (nt*16 + l15)*144;
                short8 b0 = *(const short8*)(rowp + q16);
                short8 b1 = *(const short8*)(rowp + 64 + q16);
                f32x4 z = {0.f, 0.f, 0.f, 0.f};
                z = MFMA(a0, b0, z);
                f32x4 v = MFMA(a1, b1, z);
                v = v + bb3;
                const int sg = base + nt*16 + l15;
                if (sg < n) {
                    float* op = out + (size_t)sg*19 + 3 + q*4;
                    op[0] = (q == 0) ? fmaxf(v[0], 0.f) : v[0];
                    op[1] = v[1];
                    op[2] = v[2];
                    op[3] = v[3];
                }
                if (q == 0) {   // geo slots 49..51 (df rows 1..3)
                    *(ushort*)(rowp + 98)  = (ushort)bf16rne(v[1]);
                    *(uint*)  (rowp + 100) = packbf(v[2], v[3]);
                } else {        // geo slots 48+4q .. 48+4q+3
                    uint2 g;
                    g.x = packbf(v[0], v[1]);
                    g.y = packbf(v[2], v[3]);
                    *(uint2*)(rowp + 96 + 8*q) = g;
                }
            }
        }
        // ---- per-lane: dir MLP (fp32 scalar) + app gather -> cin ----
        {
            const float dx = dirs[3*sc], dy = dirs[3*sc+1], dz = dirs[3*sc+2];
            float e1[16];
#pragma unroll
            for (int j = 0; j < 16; ++j)
                e1[j] = fmaxf(fmaf(dx, dir_w1[j],
                              fmaf(dy, dir_w1[16+j],
                              fmaf(dz, dir_w1[32+j], dir_b1[j]))), 0.f);
            float ed[16];
#pragma unroll
            for (int j = 0; j < 16; ++j) ed[j] = dir_b2[j];
#pragma unroll
            for (int i = 0; i < 16; ++i) {
                const float e = e1[i];
#pragma unroll
                for (int j = 0; j < 16; ++j) ed[j] = fmaf(e, dir_w2[i*16+j], ed[j]);
            }
            const int cam = cam_idx[sc];
            const float4* ap = (const float4*)(app_emb + (size_t)cam*32);
            uint pk[16];
#pragma unroll
            for (int qd = 0; qd < 8; ++qd) {
                const float4 vv = ap[qd];
                pk[2*qd]   = packbf(vv.x, vv.y);
                pk[2*qd+1] = packbf(vv.z, vv.w);
            }
            arow[0] = make_uint4(pk[0],  pk[1],  pk[2],  pk[3]);   // app 0..31
            arow[1] = make_uint4(pk[4],  pk[5],  pk[6],  pk[7]);
            arow[2] = make_uint4(pk[8],  pk[9],  pk[10], pk[11]);
            arow[3] = make_uint4(pk[12], pk[13], pk[14], pk[15]);
            uint ep[8];
#pragma unroll
            for (int j = 0; j < 8; ++j) ep[j] = packbf(ed[2*j], ed[2*j+1]);
            arow[4] = make_uint4(ep[0], ep[1], ep[2], ep[3]);      // edir 32..47
            arow[5] = make_uint4(ep[4], ep[5], ep[6], ep[7]);
            *(ushort*)(wact + lane*144 + 96) = 0;                  // pad slot 48
        }
        // ---- col1, col2: 64 -> 64, relu ----
        layer64(wact, aC1, smem + CB1_OFF, l15, q);
        layer64(wact, aC2, smem + CB2_OFF, l15, q);
        // ---- col3: 64 -> 3 (rows 0..2 of a 16-row tile), sigmoid ----
        {
            short8 a0 = *(const short8*)(smem + C3_OFF + l15*144 + q16);
            short8 a1 = *(const short8*)(smem + C3_OFF + l15*144 + 64 + q16);
            f32x4 bbc = *(const f32x4*)(smem + CB3_OFF);
#pragma unroll
            for (int nt = 0; nt < 4; ++nt) {
                char* rowp = wact + (nt*16 + l15)*144;
                short8 b0 = *(const short8*)(rowp + q16);
                short8 b1 = *(const short8*)(rowp + 64 + q16);
                f32x4 z = {0.f, 0.f, 0.f, 0.f};
                z = MFMA(a0, b0, z);
                f32x4 v = MFMA(a1, b1, z);
                const int sg = base + nt*16 + l15;
                if (q == 0 && sg < n) {
                    float* op = out + (size_t)sg*19;
                    op[0] = 1.f / (1.f + __expf(-(v[0] + bbc[0])));
                    op[1] = 1.f / (1.f + __expf(-(v[1] + bbc[1])));
                    op[2] = 1.f / (1.f + __expf(-(v[2] + bbc[2])));
                }
            }
        }
    }
}

extern "C" void kernel_launch(void* const* d_in, const int* in_sizes, int n_in,
                              void* d_out, int out_size, void* d_ws, size_t ws_size,
                              hipStream_t stream)
{
    const float* ray  = (const float*)d_in[0];
    const float* dirs = (const float*)d_in[1];
    const int*   cam  = (const int*)  d_in[2];
    const float* aabb = (const float*)d_in[3];
    const float* ht   = (const float*)d_in[4];
    const float* dw1  = (const float*)d_in[5];
    const float* db1  = (const float*)d_in[6];
    const float* dw2  = (const float*)d_in[7];
    const float* db2  = (const float*)d_in[8];
    const float* nw1  = (const float*)d_in[9];
    const float* nb1  = (const float*)d_in[10];
    const float* nw2  = (const float*)d_in[11];
    const float* nb2  = (const float*)d_in[12];
    const float* nw3  = (const float*)d_in[13];
    const float* nb3  = (const float*)d_in[14];
    const float* cw1  = (const float*)d_in[15];
    const float* cb1  = (const float*)d_in[16];
    const float* cw2  = (const float*)d_in[17];
    const float* cb2  = (const float*)d_in[18];
    const float* cw3  = (const float*)d_in[19];
    const float* cb3  = (const float*)d_in[20];
    const float* app  = (const float*)d_in[21];
    float* out = (float*)d_out;

    const int n = in_sizes[0] / 3;

    // Reproduce Python's RES (same libm): GROWTH = exp((ln2048-ln16)/15)
    EncC enc;
    const double growth = exp((log(2048.0) - log(16.0)) / 15.0);
    for (int i = 0; i < 16; ++i) {
        const int r = (int)(16.0 * pow(growth, (double)i));
        enc.rf[i] = (float)(r - 1);
    }

    const int ntiles = (n + 255) / 256;
    const int grid = ntiles < 512 ? ntiles : 512;
    nerf_mfma<<<grid, 256, 0, stream>>>(
        ray, dirs, cam, aabb, ht,
        dw1, db1, dw2, db2,
        nw1, nb1, nw2, nb2, nw3, nb3,
        cw1, cb1, cw2, cb2, cw3, cb3,
        app, out, n, enc);
}

// Round 3
// 418.253 us; speedup vs baseline: 5.3916x; 1.0519x over previous
//
#include <hip/hip_runtime.h>
#include <math.h>

// NerfactoModel fused forward, MFMA version r3.
// Per wave: 64 samples. Acts in per-wave LDS [64 x 72 bf16, stride 144B].
// bf16 packing = v_perm_b32 truncation (1 inst / 2 values).
// Biases ride the MFMA C-initializer (ds_read_b128, no v_add).
// grid=768, 3 blocks/CU (LDS 48KB*3 = 144KB < 160KB).

typedef short short8 __attribute__((ext_vector_type(8)));
typedef float f32x4 __attribute__((ext_vector_type(4)));
typedef float f32x4a __attribute__((ext_vector_type(4), aligned(4)));
typedef float f32x2a __attribute__((ext_vector_type(2), aligned(4)));
typedef unsigned int uint;
typedef unsigned short ushort;

struct EncC { float rf[16]; };   // (RES[l]-1) as float

#define PY 2481   // 2654435761 % 4096
#define PZ 1941   // 805459861 % 4096

#define MFMA(A,B,C) __builtin_amdgcn_mfma_f32_16x16x32_bf16(A, B, C, 0, 0, 0)

// ---- LDS layout (bytes) ----
#define W1_OFF   0        // dens_w1^T  64 x 40 bf16 (5120)
#define W3_OFF   5120     // dens_w3^T  16 x 72 bf16 (2304)
#define C3_OFF   7424     // col_w3^T   16 x 72 bf16 (2304)
#define DB1_OFF  9728     // f32 biases
#define DB2_OFF  9984
#define DB3_OFF  10240
#define CB1_OFF  10304
#define CB2_OFF  10560
#define CB3_OFF  10816
// staging-only region (freed after A-frag preload), reused by ACT:
#define W2_OFF   10848    // dens_w2^T  64 x 72 (9216)
#define C1_OFF   20064    // col_w1^T (permuted K) 64 x 72 (9216)
#define C2_OFF   29280    // col_w2^T   64 x 72 (9216)
#define ACT_OFF  10848    // 4 waves x 64 rows x 144 B = 36864
#define LDS_BYTES 47712

__device__ __forceinline__ uint bf16rne(float x) {
    uint u = __builtin_bit_cast(uint, x);
    return (u + 0x7fffu + ((u >> 16) & 1u)) >> 16;
}
// truncation pack: result = hi[31:16] | lo[31:16]>>16  (one v_perm_b32)
__device__ __forceinline__ uint pktr(float lo, float hi) {
    return __builtin_amdgcn_perm(__builtin_bit_cast(uint, hi),
                                 __builtin_bit_cast(uint, lo), 0x07060302u);
}

// writeback: relu + bf16 trunc-pack, in place (bias already in acc).
__device__ __forceinline__ void layer_wb(const f32x4* acc, char* rowp, int q) {
#pragma unroll
    for (int mt = 0; mt < 4; ++mt) {
        const f32x4 v = acc[mt];
        uint2 pw;
        pw.x = pktr(fmaxf(v[0], 0.f), fmaxf(v[1], 0.f));
        pw.y = pktr(fmaxf(v[2], 0.f), fmaxf(v[3], 0.f));
        *(uint2*)(rowp + mt*32 + q*8) = pw;
    }
}

// full 64->64 layer (K=64), A-frags persistent in registers, bias as C-init.
__device__ __forceinline__ void layer64(char* wact, const short8* aw,
                                        const char* biasp, int l15, int q) {
    const int q16 = q * 16;
    f32x4 bf[4];
#pragma unroll
    for (int mt = 0; mt < 4; ++mt)
        bf[mt] = *(const f32x4*)(biasp + mt*64 + q16);
#pragma unroll
    for (int nt = 0; nt < 4; ++nt) {
        char* rowp = wact + (nt*16 + l15)*144;
        short8 b0 = *(const short8*)(rowp + q16);
        short8 b1 = *(const short8*)(rowp + 64 + q16);
        f32x4 acc[4];
#pragma unroll
        for (int mt = 0; mt < 4; ++mt) {
            f32x4 z = MFMA(aw[2*mt], b0, bf[mt]);
            acc[mt] = MFMA(aw[2*mt + 1], b1, z);
        }
        layer_wb(acc, rowp, q);
    }
}

__global__ __launch_bounds__(256, 3)
void nerf_mfma(const float* __restrict__ ray, const float* __restrict__ dirs,
               const int* __restrict__ cam_idx, const float* __restrict__ aabb,
               const float* __restrict__ ht,
               const float* __restrict__ dir_w1, const float* __restrict__ dir_b1,
               const float* __restrict__ dir_w2, const float* __restrict__ dir_b2,
               const float* __restrict__ dens_w1, const float* __restrict__ dens_b1,
               const float* __restrict__ dens_w2, const float* __restrict__ dens_b2,
               const float* __restrict__ dens_w3, const float* __restrict__ dens_b3,
               const float* __restrict__ col_w1, const float* __restrict__ col_b1,
               const float* __restrict__ col_w2, const float* __restrict__ col_b2,
               const float* __restrict__ col_w3, const float* __restrict__ col_b3,
               const float* __restrict__ app_emb,
               float* __restrict__ out, int n, EncC enc)
{
    __shared__ __align__(16) char smem[LDS_BYTES];
    const int t = threadIdx.x;

    // ---- zero weight staging area (pad slots must read as 0) ----
    {
        uint* z = (uint*)smem;
        for (int i = t; i < 38496/4; i += 256) z[i] = 0;
    }
    __syncthreads();
    // ---- stage weights: bf16 (RNE, once per block), transposed [out][in] ----
    {
        ushort* w1t = (ushort*)(smem + W1_OFF);
        for (int e = t; e < 2048; e += 256) w1t[(e&63)*40 + (e>>6)] = (ushort)bf16rne(dens_w1[e]);
        ushort* w2t = (ushort*)(smem + W2_OFF);
        for (int e = t; e < 4096; e += 256) w2t[(e&63)*72 + (e>>6)] = (ushort)bf16rne(dens_w2[e]);
        ushort* w3t = (ushort*)(smem + W3_OFF);
        for (int e = t; e < 1024; e += 256) w3t[(e&15)*72 + (e>>4)] = (ushort)bf16rne(dens_w3[e]);
        ushort* c1t = (ushort*)(smem + C1_OFF);
        for (int e = t; e < 4032; e += 256) {
            int in = e >> 6, o = e & 63;
            int pk = (in < 15) ? (in + 49) : ((in < 31) ? (in + 17) : (in - 31));
            c1t[o*72 + pk] = (ushort)bf16rne(col_w1[e]);
        }
        ushort* c2t = (ushort*)(smem + C2_OFF);
        for (int e = t; e < 4096; e += 256) c2t[(e&63)*72 + (e>>6)] = (ushort)bf16rne(col_w2[e]);
        ushort* c3t = (ushort*)(smem + C3_OFF);
        for (int e = t; e < 192; e += 256) c3t[(e%3)*72 + (e/3)] = (ushort)bf16rne(col_w3[e]);
        if (t < 64) {
            *(float*)(smem + DB1_OFF + t*4) = dens_b1[t];
            *(float*)(smem + DB2_OFF + t*4) = dens_b2[t];
            *(float*)(smem + CB1_OFF + t*4) = col_b1[t];
            *(float*)(smem + CB2_OFF + t*4) = col_b2[t];
        }
        if (t < 16) *(float*)(smem + DB3_OFF + t*4) = dens_b3[t];
        if (t < 4)  *(float*)(smem + CB3_OFF + t*4) = (t < 3) ? col_b3[t] : 0.f;
    }
    __syncthreads();

    const int w = t >> 6, lane = t & 63, l15 = lane & 15, q = lane >> 4;
    const int q16 = q * 16;
    char* wact = smem + ACT_OFF + w*9216;

    // ---- preload persistent A-frags for the three 64x64 layers (96 VGPRs) ----
    short8 aD2[8], aC1[8], aC2[8];
#pragma unroll
    for (int mt = 0; mt < 4; ++mt)
#pragma unroll
        for (int kk = 0; kk < 2; ++kk) {
            const int ro = (mt*16 + l15)*144 + kk*64 + q16;
            aD2[mt*2+kk] = *(const short8*)(smem + W2_OFF + ro);
            aC1[mt*2+kk] = *(const short8*)(smem + C1_OFF + ro);
            aC2[mt*2+kk] = *(const short8*)(smem + C2_OFF + ro);
        }
    __syncthreads();   // staging area now reusable as act buffers

    const float a0x = aabb[0], a0y = aabb[1], a0z = aabb[2];
    const float ivx = 1.f/(aabb[3]-a0x), ivy = 1.f/(aabb[4]-a0y), ivz = 1.f/(aabb[5]-a0z);

    const int ntiles = (n + 255) >> 8;
    for (int tile = blockIdx.x; tile < ntiles; tile += gridDim.x) {
        const int base = tile*256 + w*64;
        if (base >= n) continue;               // wave-uniform
        const bool full = (base + 64 <= n);    // wave-uniform (true for n%64==0)
        const int sc = full ? (base + lane) : min(base + lane, n - 1);
        float* otile = out + (size_t)base * 19;

        // ---- hash encoding -> act feats 0..31 ----
        float px = fminf(fmaxf((ray[3*sc  ] - a0x)*ivx, 0.f), 1.f);
        float py = fminf(fmaxf((ray[3*sc+1] - a0y)*ivy, 0.f), 1.f);
        float pz = fminf(fmaxf((ray[3*sc+2] - a0z)*ivz, 0.f), 1.f);
        uint encp[16];
#pragma unroll
        for (int l = 0; l < 16; ++l) {
            const float rf = enc.rf[l];
            const int cx = (int)(px*rf), cy = (int)(py*rf), cz = (int)(pz*rf);
            const int h = (cx + cy*PY + cz*PZ) & 4095;
            const float2 f = *(const float2*)(ht + (((l<<12) + h) << 1));
            encp[l] = pktr(f.x, f.y);
        }
        uint4* arow = (uint4*)(wact + lane*144);
        arow[0] = make_uint4(encp[0],  encp[1],  encp[2],  encp[3]);
        arow[1] = make_uint4(encp[4],  encp[5],  encp[6],  encp[7]);
        arow[2] = make_uint4(encp[8],  encp[9],  encp[10], encp[11]);
        arow[3] = make_uint4(encp[12], encp[13], encp[14], encp[15]);

        // ---- dens1: 32 -> 64, relu (K=32), bias as C-init ----
        {
            short8 a1[4];
            f32x4 bf[4];
#pragma unroll
            for (int mt = 0; mt < 4; ++mt) {
                a1[mt] = *(const short8*)(smem + W1_OFF + (mt*16 + l15)*80 + q16);
                bf[mt] = *(const f32x4*)(smem + DB1_OFF + mt*64 + q16);
            }
#pragma unroll
            for (int nt = 0; nt < 4; ++nt) {
                char* rowp = wact + (nt*16 + l15)*144;
                short8 b = *(const short8*)(rowp + q16);
                f32x4 acc[4];
#pragma unroll
                for (int mt = 0; mt < 4; ++mt)
                    acc[mt] = MFMA(a1[mt], b, bf[mt]);
                layer_wb(acc, rowp, q);
            }
        }
        // ---- dens2: 64 -> 64, relu ----
        layer64(wact, aD2, smem + DB2_OFF, l15, q);
        // ---- dens3: 64 -> 16 ; density+geo out, geo -> cin slots 49..63 ----
        {
            short8 a0 = *(const short8*)(smem + W3_OFF + l15*144 + q16);
            short8 a1 = *(const short8*)(smem + W3_OFF + l15*144 + 64 + q16);
            f32x4 bb3 = *(const f32x4*)(smem + DB3_OFF + q16);
#pragma unroll
            for (int nt = 0; nt < 4; ++nt) {
                char* rowp = wact + (nt*16 + l15)*144;
                short8 b0 = *(const short8*)(rowp + q16);
                short8 b1 = *(const short8*)(rowp + 64 + q16);
                f32x4 z = MFMA(a0, b0, bb3);
                f32x4 v = MFMA(a1, b1, z);
                // geo slots: q0 writes [pad=0, g49, g50, g51]; q>0 writes 4 geo
                uint2 g;
                g.x = pktr(q == 0 ? 0.f : v[0], v[1]);
                g.y = pktr(v[2], v[3]);
                *(uint2*)(rowp + 96 + 8*q) = g;
                if (q == 0) v[0] = fmaxf(v[0], 0.f);   // density relu
                const int sg = nt*16 + l15;
                if (full || base + sg < n)
                    *(f32x4a*)(otile + sg*19 + 3 + q16/4) = v;
            }
        }
        // ---- per-lane: dir MLP (fp32 scalar) + app gather -> cin ----
        {
            const float dx = dirs[3*sc], dy = dirs[3*sc+1], dz = dirs[3*sc+2];
            float e1[16];
#pragma unroll
            for (int j = 0; j < 16; ++j)
                e1[j] = fmaxf(fmaf(dx, dir_w1[j],
                              fmaf(dy, dir_w1[16+j],
                              fmaf(dz, dir_w1[32+j], dir_b1[j]))), 0.f);
            float ed[16];
#pragma unroll
            for (int j = 0; j < 16; ++j) ed[j] = dir_b2[j];
#pragma unroll
            for (int i = 0; i < 16; ++i) {
                const float e = e1[i];
#pragma unroll
                for (int j = 0; j < 16; ++j) ed[j] = fmaf(e, dir_w2[i*16+j], ed[j]);
            }
            const int cam = cam_idx[sc];
            const float4* ap = (const float4*)(app_emb + (size_t)cam*32);
            uint pk[16];
#pragma unroll
            for (int qd = 0; qd < 8; ++qd) {
                const float4 vv = ap[qd];
                pk[2*qd]   = pktr(vv.x, vv.y);
                pk[2*qd+1] = pktr(vv.z, vv.w);
            }
            arow[0] = make_uint4(pk[0],  pk[1],  pk[2],  pk[3]);   // app 0..31
            arow[1] = make_uint4(pk[4],  pk[5],  pk[6],  pk[7]);
            arow[2] = make_uint4(pk[8],  pk[9],  pk[10], pk[11]);
            arow[3] = make_uint4(pk[12], pk[13], pk[14], pk[15]);
            uint ep[8];
#pragma unroll
            for (int j = 0; j < 8; ++j) ep[j] = pktr(ed[2*j], ed[2*j+1]);
            arow[4] = make_uint4(ep[0], ep[1], ep[2], ep[3]);      // edir 32..47
            arow[5] = make_uint4(ep[4], ep[5], ep[6], ep[7]);
        }
        // ---- col1, col2: 64 -> 64, relu ----
        layer64(wact, aC1, smem + CB1_OFF, l15, q);
        layer64(wact, aC2, smem + CB2_OFF, l15, q);
        // ---- col3: 64 -> 3 (rows 0..2), sigmoid ----
        {
            short8 a0 = *(const short8*)(smem + C3_OFF + l15*144 + q16);
            short8 a1 = *(const short8*)(smem + C3_OFF + l15*144 + 64 + q16);
            f32x4 bbc = *(const f32x4*)(smem + CB3_OFF);
#pragma unroll
            for (int nt = 0; nt < 4; ++nt) {
                char* rowp = wact + (nt*16 + l15)*144;
                short8 b0 = *(const short8*)(rowp + q16);
                short8 b1 = *(const short8*)(rowp + 64 + q16);
                f32x4 z = MFMA(a0, b0, bbc);
                f32x4 v = MFMA(a1, b1, z);
                const int sg = nt*16 + l15;
                if (q == 0 && (full || base + sg < n)) {
                    float* op = otile + sg*19;
                    f32x2a r01;
                    r01[0] = 1.f / (1.f + __expf(-v[0]));
                    r01[1] = 1.f / (1.f + __expf(-v[1]));
                    *(f32x2a*)op = r01;
                    op[2] = 1.f / (1.f + __expf(-v[2]));
                }
            }
        }
    }
}

extern "C" void kernel_launch(void* const* d_in, const int* in_sizes, int n_in,
                              void* d_out, int out_size, void* d_ws, size_t ws_size,
                              hipStream_t stream)
{
    const float* ray  = (const float*)d_in[0];
    const float* dirs = (const float*)d_in[1];
    const int*   cam  = (const int*)  d_in[2];
    const float* aabb = (const float*)d_in[3];
    const float* ht   = (const float*)d_in[4];
    const float* dw1  = (const float*)d_in[5];
    const float* db1  = (const float*)d_in[6];
    const float* dw2  = (const float*)d_in[7];
    const float* db2  = (const float*)d_in[8];
    const float* nw1  = (const float*)d_in[9];
    const float* nb1  = (const float*)d_in[10];
    const float* nw2  = (const float*)d_in[11];
    const float* nb2  = (const float*)d_in[12];
    const float* nw3  = (const float*)d_in[13];
    const float* nb3  = (const float*)d_in[14];
    const float* cw1  = (const float*)d_in[15];
    const float* cb1  = (const float*)d_in[16];
    const float* cw2  = (const float*)d_in[17];
    const float* cb2  = (const float*)d_in[18];
    const float* cw3  = (const float*)d_in[19];
    const float* cb3  = (const float*)d_in[20];
    const float* app  = (const float*)d_in[21];
    float* out = (float*)d_out;

    const int n = in_sizes[0] / 3;

    // Reproduce Python's RES (same libm): GROWTH = exp((ln2048-ln16)/15)
    EncC enc;
    const double growth = exp((log(2048.0) - log(16.0)) / 15.0);
    for (int i = 0; i < 16; ++i) {
        const int r = (int)(16.0 * pow(growth, (double)i));
        enc.rf[i] = (float)(r - 1);
    }

    const int ntiles = (n + 255) / 256;
    const int grid = ntiles < 768 ? ntiles : 768;
    nerf_mfma<<<grid, 256, 0, stream>>>(
        ray, dirs, cam, aabb, ht,
        dw1, db1, dw2, db2,
        nw1, nb1, nw2, nb2, nw3, nb3,
        cw1, cb1, cw2, cb2, cw3, cb3,
        app, out, n, enc);
}